// Round 1
// baseline (3097.898 us; speedup 1.0000x reference)
//
#include <hip/hip_runtime.h>
#include <hip/hip_bf16.h>

typedef __hip_bfloat16 bf16;

#define T_TOK 2048
#define HDIM  2048
#define NEXP  64
#define IDIM  768
#define TOPK  8
#define OUT_OFF (T_TOK * HDIM)      // 4194304 floats: out, then router_logits
#define NPAIR (T_TOK * TOPK)        // 16384

// ---- workspace layout (bytes) ----
#define WS_TOPK_IDX  0                         // int [T][8]        64KB
#define WS_TOPK_W    (64 * 1024)               // float [T][8]      64KB
#define WS_PAIR_TOK  (128 * 1024)              // int [NPAIR]       64KB
#define WS_SLOT_OF   (192 * 1024)              // int [T][8]        64KB
#define WS_COUNTS    (256 * 1024)              // int [64]
#define WS_OFFSETS   (257 * 1024)              // int [65]
#define WS_CURSOR    (258 * 1024)              // int [64]
#define WS_H         (1024 * 1024)             // bf16 [NPAIR][IDIM]   25.2MB
#define WS_PARTIAL   (WS_H + (size_t)NPAIR * IDIM * 2)  // bf16 [NPAIR][HDIM] 67.1MB

__device__ __forceinline__ float bf_to_f(unsigned short u) {
    return __uint_as_float(((unsigned int)u) << 16);
}

// ---------------- kernel 1: router logits [T,E] ----------------
// block 256 = 4 waves, one wave per token; lane = expert
__global__ __launch_bounds__(256) void router_kernel(
    const float* __restrict__ x, const float* __restrict__ rw,
    float* __restrict__ logits) {
    int wave = threadIdx.x >> 6;
    int lane = threadIdx.x & 63;
    int t = blockIdx.x * 4 + wave;
    const float4* x4 = (const float4*)(x + (size_t)t * HDIM);
    float acc = 0.f;
    for (int h4 = 0; h4 < HDIM / 4; ++h4) {
        float4 xv = x4[h4];
        int h = h4 * 4;
        acc = fmaf(xv.x, rw[(h + 0) * NEXP + lane], acc);
        acc = fmaf(xv.y, rw[(h + 1) * NEXP + lane], acc);
        acc = fmaf(xv.z, rw[(h + 2) * NEXP + lane], acc);
        acc = fmaf(xv.w, rw[(h + 3) * NEXP + lane], acc);
    }
    logits[t * NEXP + lane] = acc;
}

// ---------------- kernel 2: softmax + top-8 + expert counts ----------------
// one wave per token; lane = expert
__global__ __launch_bounds__(64) void topk_kernel(
    const float* __restrict__ logits, int* __restrict__ topk_idx,
    float* __restrict__ topk_w, int* __restrict__ counts) {
    int t = blockIdx.x;
    int lane = threadIdx.x;
    float lg = logits[t * NEXP + lane];
    float mx = lg;
    for (int off = 32; off; off >>= 1) mx = fmaxf(mx, __shfl_xor(mx, off));
    float ex = expf(lg - mx);
    float sum = ex;
    for (int off = 32; off; off >>= 1) sum += __shfl_xor(sum, off);
    float prob = ex / sum;

    float pr = prob;
    float myv = 0.f;
    int myidx = 0;
    float ksum = 0.f;
    for (int k = 0; k < TOPK; ++k) {
        float v = pr;
        int idx = lane;
        for (int off = 32; off; off >>= 1) {
            float ov = __shfl_xor(v, off);
            int oi = __shfl_xor(idx, off);
            if (ov > v || (ov == v && oi < idx)) { v = ov; idx = oi; }
        }
        ksum += v;
        if (lane == k) { myidx = idx; myv = v; }
        if (lane == idx) pr = -1.f;   // remove winner
    }
    if (lane < TOPK) {
        topk_idx[t * TOPK + lane] = myidx;
        topk_w[t * TOPK + lane] = myv / ksum;
        atomicAdd(&counts[myidx], 1);
    }
}

// ---------------- kernel 3: exclusive scan of counts -> offsets; zero cursor ----------------
__global__ __launch_bounds__(64) void scan_kernel(
    const int* __restrict__ counts, int* __restrict__ offsets, int* __restrict__ cursor) {
    int lane = threadIdx.x;
    int c = counts[lane];
    int incl = c;
    for (int off = 1; off < 64; off <<= 1) {
        int tt = __shfl_up(incl, off);
        if (lane >= off) incl += tt;
    }
    offsets[lane] = incl - c;
    if (lane == 63) offsets[64] = incl;
    cursor[lane] = 0;
}

// ---------------- kernel 4: scatter pairs into expert-sorted order ----------------
__global__ __launch_bounds__(256) void scatter_kernel(
    const int* __restrict__ topk_idx, const int* __restrict__ offsets,
    int* __restrict__ cursor, int* __restrict__ pair_token, int* __restrict__ slot_of) {
    int i = blockIdx.x * 256 + threadIdx.x;   // pair id = t*8+k
    if (i >= NPAIR) return;
    int t = i >> 3;
    int e = topk_idx[i];
    int pos = atomicAdd(&cursor[e], 1);
    int slot = offsets[e] + pos;
    pair_token[slot] = t;
    slot_of[i] = slot;
}

// ---------------- kernel 5: grouped gate/up GEMM + SwiGLU -> h (bf16) ----------------
#define TM  32
#define TNB 64
#define BK  32

__global__ __launch_bounds__(256) void gateup_kernel(
    const float* __restrict__ x, const float* __restrict__ gate_w,
    const float* __restrict__ up_w, const int* __restrict__ offsets,
    const int* __restrict__ pair_token, bf16* __restrict__ hbuf) {
    int e = blockIdx.x;
    int ntile = blockIdx.z;            // 0..11 (I tiles of 64)
    int off = offsets[e];
    int cnt = offsets[e + 1] - off;

    __shared__ float xs[BK][36];       // transposed: xs[kk][r]
    __shared__ float gs[BK][TNB];
    __shared__ float us[BK][TNB];
    __shared__ int toks[TM];

    int tid = threadIdx.x;
    int lane = tid & 63;
    int wave = tid >> 6;
    const float* gbase = gate_w + (size_t)e * HDIM * IDIM + ntile * TNB;
    const float* ubase = up_w   + (size_t)e * HDIM * IDIM + ntile * TNB;

    for (int mt = blockIdx.y; mt * TM < cnt; mt += gridDim.y) {
        int m0 = mt * TM;
        if (tid < TM) {
            int p = off + m0 + tid;
            toks[tid] = pair_token[p < NPAIR ? p : NPAIR - 1];
        }
        float accg[8] = {0.f, 0.f, 0.f, 0.f, 0.f, 0.f, 0.f, 0.f};
        float accu[8] = {0.f, 0.f, 0.f, 0.f, 0.f, 0.f, 0.f, 0.f};
        __syncthreads();   // toks ready

        for (int h0 = 0; h0 < HDIM; h0 += BK) {
            {   // stage x tile (transposed)
                int r = tid >> 3;
                int kk4 = (tid & 7) * 4;
                const float* xr = x + (size_t)toks[r] * HDIM + h0 + kk4;
                float4 xv = *(const float4*)xr;
                xs[kk4 + 0][r] = xv.x;
                xs[kk4 + 1][r] = xv.y;
                xs[kk4 + 2][r] = xv.z;
                xs[kk4 + 3][r] = xv.w;
            }
            #pragma unroll
            for (int q = 0; q < 2; ++q) {   // stage gate/up tiles
                int f4 = tid + q * 256;      // 0..511
                int row = f4 >> 4;
                int c4 = (f4 & 15) * 4;
                *(float4*)&gs[row][c4] = *(const float4*)(gbase + (size_t)(h0 + row) * IDIM + c4);
                *(float4*)&us[row][c4] = *(const float4*)(ubase + (size_t)(h0 + row) * IDIM + c4);
            }
            __syncthreads();
            int r0 = wave * 8;
            #pragma unroll 8
            for (int kk = 0; kk < BK; ++kk) {
                float g = gs[kk][lane];
                float u = us[kk][lane];
                #pragma unroll
                for (int j = 0; j < 8; ++j) {
                    float xv = xs[kk][r0 + j];
                    accg[j] = fmaf(xv, g, accg[j]);
                    accu[j] = fmaf(xv, u, accu[j]);
                }
            }
            __syncthreads();
        }
        int r0 = wave * 8;
        #pragma unroll
        for (int j = 0; j < 8; ++j) {
            int row = m0 + r0 + j;
            if (row < cnt) {
                float g = accg[j];
                float hv = (g / (1.f + expf(-g))) * accu[j];   // silu(g)*u
                hbuf[(size_t)(off + row) * IDIM + ntile * TNB + lane] = __float2bfloat16(hv);
            }
        }
        __syncthreads();   // protect toks/LDS before next mt iteration
    }
}

// ---------------- kernel 6: grouped down GEMM -> per-pair partial (bf16) ----------------
__global__ __launch_bounds__(256) void down_kernel(
    const bf16* __restrict__ hbuf, const float* __restrict__ down_w,
    const int* __restrict__ offsets, bf16* __restrict__ partial) {
    int e = blockIdx.x;
    int ntile = blockIdx.z;            // 0..31 (H tiles of 64)
    int off = offsets[e];
    int cnt = offsets[e + 1] - off;

    __shared__ float hs[BK][36];       // transposed
    __shared__ float ds[BK][TNB];

    int tid = threadIdx.x;
    int lane = tid & 63;
    int wave = tid >> 6;
    const float* dbase = down_w + (size_t)e * IDIM * HDIM + ntile * TNB;

    for (int mt = blockIdx.y; mt * TM < cnt; mt += gridDim.y) {
        int m0 = mt * TM;
        float acc[8] = {0.f, 0.f, 0.f, 0.f, 0.f, 0.f, 0.f, 0.f};

        for (int k0 = 0; k0 < IDIM; k0 += BK) {
            {   // stage h tile (bf16 -> f32, transposed)
                int r = tid >> 3;
                int kk4 = (tid & 7) * 4;
                int row = m0 + r;
                int src = off + (row < cnt ? row : 0);
                const unsigned short* hp = (const unsigned short*)hbuf + (size_t)src * IDIM + k0 + kk4;
                ushort4 hv = *(const ushort4*)hp;
                hs[kk4 + 0][r] = bf_to_f(hv.x);
                hs[kk4 + 1][r] = bf_to_f(hv.y);
                hs[kk4 + 2][r] = bf_to_f(hv.z);
                hs[kk4 + 3][r] = bf_to_f(hv.w);
            }
            #pragma unroll
            for (int q = 0; q < 2; ++q) {
                int f4 = tid + q * 256;
                int row = f4 >> 4;
                int c4 = (f4 & 15) * 4;
                *(float4*)&ds[row][c4] = *(const float4*)(dbase + (size_t)(k0 + row) * HDIM + c4);
            }
            __syncthreads();
            int r0 = wave * 8;
            #pragma unroll 8
            for (int kk = 0; kk < BK; ++kk) {
                float d = ds[kk][lane];
                #pragma unroll
                for (int j = 0; j < 8; ++j) {
                    acc[j] = fmaf(hs[kk][r0 + j], d, acc[j]);
                }
            }
            __syncthreads();
        }
        int r0 = wave * 8;
        #pragma unroll
        for (int j = 0; j < 8; ++j) {
            int row = m0 + r0 + j;
            if (row < cnt) {
                partial[(size_t)(off + row) * HDIM + ntile * TNB + lane] = __float2bfloat16(acc[j]);
            }
        }
        __syncthreads();
    }
}

// ---------------- kernel 7: weighted 8-way reduce -> out ----------------
__global__ __launch_bounds__(256) void reduce_kernel(
    const bf16* __restrict__ partial, const int* __restrict__ slot_of,
    const float* __restrict__ topk_w, float* __restrict__ out) {
    int t = blockIdx.x;
    int j = blockIdx.y * 256 + threadIdx.x;
    __shared__ int ss[8];
    __shared__ float sw[8];
    if (threadIdx.x < 8) {
        ss[threadIdx.x] = slot_of[t * TOPK + threadIdx.x];
        sw[threadIdx.x] = topk_w[t * TOPK + threadIdx.x];
    }
    __syncthreads();
    float acc = 0.f;
    #pragma unroll
    for (int k = 0; k < TOPK; ++k) {
        unsigned short hb = ((const unsigned short*)partial)[(size_t)ss[k] * HDIM + j];
        acc = fmaf(sw[k], bf_to_f(hb), acc);
    }
    out[(size_t)t * HDIM + j] = acc;
}

extern "C" void kernel_launch(void* const* d_in, const int* in_sizes, int n_in,
                              void* d_out, int out_size, void* d_ws, size_t ws_size,
                              hipStream_t stream) {
    const float* x  = (const float*)d_in[0];
    const float* rw = (const float*)d_in[1];
    const float* gw = (const float*)d_in[2];
    const float* uw = (const float*)d_in[3];
    const float* dw = (const float*)d_in[4];
    float* out = (float*)d_out;
    float* logits = out + OUT_OFF;

    char* ws = (char*)d_ws;
    int*   topk_idx   = (int*)(ws + WS_TOPK_IDX);
    float* topk_w     = (float*)(ws + WS_TOPK_W);
    int*   pair_token = (int*)(ws + WS_PAIR_TOK);
    int*   slot_of    = (int*)(ws + WS_SLOT_OF);
    int*   counts     = (int*)(ws + WS_COUNTS);
    int*   offsets    = (int*)(ws + WS_OFFSETS);
    int*   cursor     = (int*)(ws + WS_CURSOR);
    bf16*  hbuf       = (bf16*)(ws + WS_H);
    bf16*  partial    = (bf16*)(ws + WS_PARTIAL);

    hipMemsetAsync(counts, 0, NEXP * sizeof(int), stream);
    router_kernel<<<T_TOK / 4, 256, 0, stream>>>(x, rw, logits);
    topk_kernel<<<T_TOK, 64, 0, stream>>>(logits, topk_idx, topk_w, counts);
    scan_kernel<<<1, 64, 0, stream>>>(counts, offsets, cursor);
    scatter_kernel<<<NPAIR / 256, 256, 0, stream>>>(topk_idx, offsets, cursor, pair_token, slot_of);
    gateup_kernel<<<dim3(NEXP, 16, IDIM / TNB), 256, 0, stream>>>(x, gw, uw, offsets, pair_token, hbuf);
    down_kernel<<<dim3(NEXP, 16, HDIM / TNB), 256, 0, stream>>>(hbuf, dw, offsets, partial);
    reduce_kernel<<<dim3(T_TOK, HDIM / 256), 256, 0, stream>>>(partial, slot_of, topk_w, out);
}

// Round 2
// 900.793 us; speedup vs baseline: 3.4391x; 3.4391x over previous
//
#include <hip/hip_runtime.h>
#include <hip/hip_bf16.h>

typedef __hip_bfloat16 bf16;
typedef short s16x8 __attribute__((ext_vector_type(8)));
typedef unsigned short u16x8 __attribute__((ext_vector_type(8)));
typedef float f32x4 __attribute__((ext_vector_type(4)));

#define T_TOK 2048
#define HDIM  2048
#define NEXP  64
#define IDIM  768
#define TOPK  8
#define OUT_OFF (T_TOK * HDIM)      // floats: out, then router_logits
#define NPAIR (T_TOK * TOPK)        // 16384

// ---- workspace layout (bytes) ----
#define WS_TOPK_IDX  0                         // int [T][8]
#define WS_TOPK_W    (64 * 1024)               // float [T][8]
#define WS_PAIR_TOK  (128 * 1024)              // int [NPAIR]
#define WS_SLOT_OF   (192 * 1024)              // int [T][8]
#define WS_COUNTS    (256 * 1024)
#define WS_OFFSETS   (257 * 1024)
#define WS_CURSOR    (258 * 1024)
#define WS_H         (1024 * 1024)             // bf16 [NPAIR][IDIM]   25.2MB
#define WS_PARTIAL   (WS_H + (size_t)NPAIR * IDIM * 2)  // bf16 [NPAIR][HDIM] 67.1MB
// xb (bf16 [T][H], 8MB) overlaps the partial region: xb is consumed by gateup
// (only) before down writes partial.
#define WS_XB        WS_PARTIAL

__device__ __forceinline__ float bf_to_f(unsigned short u) {
    return __uint_as_float(((unsigned int)u) << 16);
}
__device__ __forceinline__ unsigned short f2bf(float f) {
    unsigned int u = __float_as_uint(f);
    unsigned int r = (u + 0x7FFFu + ((u >> 16) & 1u)) >> 16;
    return (unsigned short)r;
}

// ---------------- kernel 0: x fp32 -> bf16 ----------------
__global__ __launch_bounds__(256) void xbf_kernel(const float* __restrict__ x,
                                                  unsigned short* __restrict__ xb) {
    int i = blockIdx.x * 256 + threadIdx.x;       // one per 8 elements
    const float4* src = (const float4*)x + (size_t)i * 2;
    float4 a = src[0], b = src[1];
    u16x8 o;
    o[0] = f2bf(a.x); o[1] = f2bf(a.y); o[2] = f2bf(a.z); o[3] = f2bf(a.w);
    o[4] = f2bf(b.x); o[5] = f2bf(b.y); o[6] = f2bf(b.z); o[7] = f2bf(b.w);
    ((u16x8*)xb)[i] = o;
}

// ---------------- kernel 1: router logits [T,E] ----------------
__global__ __launch_bounds__(256) void router_kernel(
    const float* __restrict__ x, const float* __restrict__ rw,
    float* __restrict__ logits) {
    int wave = threadIdx.x >> 6;
    int lane = threadIdx.x & 63;
    int t = blockIdx.x * 4 + wave;
    const float4* x4 = (const float4*)(x + (size_t)t * HDIM);
    float acc = 0.f;
    for (int h4 = 0; h4 < HDIM / 4; ++h4) {
        float4 xv = x4[h4];
        int h = h4 * 4;
        acc = fmaf(xv.x, rw[(h + 0) * NEXP + lane], acc);
        acc = fmaf(xv.y, rw[(h + 1) * NEXP + lane], acc);
        acc = fmaf(xv.z, rw[(h + 2) * NEXP + lane], acc);
        acc = fmaf(xv.w, rw[(h + 3) * NEXP + lane], acc);
    }
    logits[t * NEXP + lane] = acc;
}

// ---------------- kernel 2: softmax + top-8 + expert counts ----------------
__global__ __launch_bounds__(64) void topk_kernel(
    const float* __restrict__ logits, int* __restrict__ topk_idx,
    float* __restrict__ topk_w, int* __restrict__ counts) {
    int t = blockIdx.x;
    int lane = threadIdx.x;
    float lg = logits[t * NEXP + lane];
    float mx = lg;
    for (int off = 32; off; off >>= 1) mx = fmaxf(mx, __shfl_xor(mx, off));
    float ex = expf(lg - mx);
    float sum = ex;
    for (int off = 32; off; off >>= 1) sum += __shfl_xor(sum, off);
    float prob = ex / sum;

    float pr = prob;
    float myv = 0.f;
    int myidx = 0;
    float ksum = 0.f;
    for (int k = 0; k < TOPK; ++k) {
        float v = pr;
        int idx = lane;
        for (int off = 32; off; off >>= 1) {
            float ov = __shfl_xor(v, off);
            int oi = __shfl_xor(idx, off);
            if (ov > v || (ov == v && oi < idx)) { v = ov; idx = oi; }
        }
        ksum += v;
        if (lane == k) { myidx = idx; myv = v; }
        if (lane == idx) pr = -1.f;
    }
    if (lane < TOPK) {
        topk_idx[t * TOPK + lane] = myidx;
        topk_w[t * TOPK + lane] = myv / ksum;
        atomicAdd(&counts[myidx], 1);
    }
}

// ---------------- kernel 3: scan -> offsets ----------------
__global__ __launch_bounds__(64) void scan_kernel(
    const int* __restrict__ counts, int* __restrict__ offsets, int* __restrict__ cursor) {
    int lane = threadIdx.x;
    int c = counts[lane];
    int incl = c;
    for (int off = 1; off < 64; off <<= 1) {
        int tt = __shfl_up(incl, off);
        if (lane >= off) incl += tt;
    }
    offsets[lane] = incl - c;
    if (lane == 63) offsets[64] = incl;
    cursor[lane] = 0;
}

// ---------------- kernel 4: scatter pairs ----------------
__global__ __launch_bounds__(256) void scatter_kernel(
    const int* __restrict__ topk_idx, const int* __restrict__ offsets,
    int* __restrict__ cursor, int* __restrict__ pair_token, int* __restrict__ slot_of) {
    int i = blockIdx.x * 256 + threadIdx.x;
    if (i >= NPAIR) return;
    int t = i >> 3;
    int e = topk_idx[i];
    int pos = atomicAdd(&cursor[e], 1);
    int slot = offsets[e] + pos;
    pair_token[slot] = t;
    slot_of[i] = slot;
}

// ================= MFMA grouped GEMMs =================
#define BM   128
#define BKS  64
#define LDP  72    // padded LDS row (elements): 144B rows, 16B-aligned

// ---------------- kernel 5: gateup (bf16 MFMA) + SwiGLU -> h ----------------
// grid (e, mt(4, stride), ntile(12)); 256 thr = 4 waves in 2x2; each wave
// owns 64 rows x 32 i-cols and computes BOTH gate and up accs.
__global__ __launch_bounds__(256) void gateup_mfma(
    const unsigned short* __restrict__ xb, const float* __restrict__ gate_w,
    const float* __restrict__ up_w, const int* __restrict__ offsets,
    const int* __restrict__ pair_token, unsigned short* __restrict__ hbuf) {
    int e = blockIdx.x;
    int ntile = blockIdx.z;                 // 0..11, 64 i-cols each
    int off = offsets[e];
    int cnt = offsets[e + 1] - off;

    __shared__ unsigned short As[BM][LDP];      // [m][k]
    __shared__ unsigned short Bg[64][LDP];      // [n][k] (transposed)
    __shared__ unsigned short Bu[64][LDP];
    __shared__ int toks[BM];

    int tid = threadIdx.x;
    int lane = tid & 63;
    int wave = tid >> 6;
    int wr = wave >> 1, wc = wave & 1;      // 2x2 wave grid
    int l15 = lane & 15, lk = (lane >> 4) * 8;

    const float* gbase = gate_w + (size_t)e * HDIM * IDIM + ntile * 64;
    const float* ubase = up_w   + (size_t)e * HDIM * IDIM + ntile * 64;

    for (int mt = blockIdx.y; mt * BM < cnt; mt += gridDim.y) {
        int m0 = mt * BM;
        if (tid < BM) {
            int p = m0 + tid;
            toks[tid] = pair_token[off + (p < cnt ? p : 0)];
        }
        f32x4 accg[4][2] = {};
        f32x4 accu[4][2] = {};
        __syncthreads();

        for (int h0 = 0; h0 < HDIM; h0 += BKS) {
            // stage A: 128x64 bf16, linear [m][k]
            #pragma unroll
            for (int q = 0; q < 4; ++q) {
                int c = tid + q * 256;
                int m = c >> 3, j = c & 7;
                *(u16x8*)&As[m][j * 8] =
                    *(const u16x8*)(xb + (size_t)toks[m] * HDIM + h0 + j * 8);
            }
            // stage B gate/up: 64k x 64n fp32 -> bf16 transposed [n][k]
            #pragma unroll
            for (int q = 0; q < 2; ++q) {
                int c = tid + q * 256;
                int nI = c & 15, kI = c >> 4;          // n4 = 4*nI, k pair = 2*kI
                const float* g0p = gbase + (size_t)(h0 + 2 * kI) * IDIM + 4 * nI;
                float4 g0 = *(const float4*)g0p;
                float4 g1 = *(const float4*)(g0p + IDIM);
                const float* u0p = ubase + (size_t)(h0 + 2 * kI) * IDIM + 4 * nI;
                float4 u0 = *(const float4*)u0p;
                float4 u1 = *(const float4*)(u0p + IDIM);
                int n = 4 * nI;
                *(unsigned int*)&Bg[n + 0][2 * kI] = (unsigned)f2bf(g0.x) | ((unsigned)f2bf(g1.x) << 16);
                *(unsigned int*)&Bg[n + 1][2 * kI] = (unsigned)f2bf(g0.y) | ((unsigned)f2bf(g1.y) << 16);
                *(unsigned int*)&Bg[n + 2][2 * kI] = (unsigned)f2bf(g0.z) | ((unsigned)f2bf(g1.z) << 16);
                *(unsigned int*)&Bg[n + 3][2 * kI] = (unsigned)f2bf(g0.w) | ((unsigned)f2bf(g1.w) << 16);
                *(unsigned int*)&Bu[n + 0][2 * kI] = (unsigned)f2bf(u0.x) | ((unsigned)f2bf(u1.x) << 16);
                *(unsigned int*)&Bu[n + 1][2 * kI] = (unsigned)f2bf(u0.y) | ((unsigned)f2bf(u1.y) << 16);
                *(unsigned int*)&Bu[n + 2][2 * kI] = (unsigned)f2bf(u0.z) | ((unsigned)f2bf(u1.z) << 16);
                *(unsigned int*)&Bu[n + 3][2 * kI] = (unsigned)f2bf(u0.w) | ((unsigned)f2bf(u1.w) << 16);
            }
            __syncthreads();

            #pragma unroll
            for (int kk = 0; kk < 2; ++kk) {
                int krow = kk * 32 + lk;
                s16x8 a[4], bg[2], bu[2];
                #pragma unroll
                for (int mr = 0; mr < 4; ++mr)
                    a[mr] = *(const s16x8*)&As[wr * 64 + mr * 16 + l15][krow];
                #pragma unroll
                for (int nr = 0; nr < 2; ++nr) {
                    bg[nr] = *(const s16x8*)&Bg[wc * 32 + nr * 16 + l15][krow];
                    bu[nr] = *(const s16x8*)&Bu[wc * 32 + nr * 16 + l15][krow];
                }
                #pragma unroll
                for (int mr = 0; mr < 4; ++mr)
                    #pragma unroll
                    for (int nr = 0; nr < 2; ++nr) {
                        accg[mr][nr] = __builtin_amdgcn_mfma_f32_16x16x32_bf16(
                            a[mr], bg[nr], accg[mr][nr], 0, 0, 0);
                        accu[mr][nr] = __builtin_amdgcn_mfma_f32_16x16x32_bf16(
                            a[mr], bu[nr], accu[mr][nr], 0, 0, 0);
                    }
            }
            __syncthreads();
        }

        // epilogue: h = silu(g)*u, bf16 store
        #pragma unroll
        for (int mr = 0; mr < 4; ++mr)
            #pragma unroll
            for (int nr = 0; nr < 2; ++nr) {
                int col = ntile * 64 + wc * 32 + nr * 16 + l15;
                #pragma unroll
                for (int reg = 0; reg < 4; ++reg) {
                    int r = m0 + wr * 64 + mr * 16 + (lane >> 4) * 4 + reg;
                    if (r < cnt) {
                        float g = accg[mr][nr][reg];
                        float u = accu[mr][nr][reg];
                        float hv = (g / (1.f + __expf(-g))) * u;
                        hbuf[(size_t)(off + r) * IDIM + col] = f2bf(hv);
                    }
                }
            }
        __syncthreads();
    }
}

// ---------------- kernel 6: down (bf16 MFMA) -> partial ----------------
// grid (e, mt(4, stride), ntile(16)); BN=128; waves 2x2, each 64x64.
__global__ __launch_bounds__(256) void down_mfma(
    const unsigned short* __restrict__ hbuf, const float* __restrict__ down_w,
    const int* __restrict__ offsets, unsigned short* __restrict__ partial) {
    int e = blockIdx.x;
    int ntile = blockIdx.z;                 // 0..15, 128 h-cols each
    int off = offsets[e];
    int cnt = offsets[e + 1] - off;

    __shared__ unsigned short As[BM][LDP];      // [m][k]
    __shared__ unsigned short Bd[128][LDP];     // [n][k]

    int tid = threadIdx.x;
    int lane = tid & 63;
    int wave = tid >> 6;
    int wr = wave >> 1, wc = wave & 1;
    int l15 = lane & 15, lk = (lane >> 4) * 8;

    const float* dbase = down_w + (size_t)e * IDIM * HDIM + ntile * 128;

    for (int mt = blockIdx.y; mt * BM < cnt; mt += gridDim.y) {
        int m0 = mt * BM;
        f32x4 acc[4][4] = {};

        for (int k0 = 0; k0 < IDIM; k0 += BKS) {
            // stage A: h rows (bf16 already), linear [m][k]
            #pragma unroll
            for (int q = 0; q < 4; ++q) {
                int c = tid + q * 256;
                int m = c >> 3, j = c & 7;
                int row = m0 + m;
                if (row >= cnt) row = cnt - 1;
                *(u16x8*)&As[m][j * 8] =
                    *(const u16x8*)(hbuf + (size_t)(off + row) * IDIM + k0 + j * 8);
            }
            // stage B: 64k x 128n fp32 -> bf16 transposed [n][k]
            #pragma unroll
            for (int q = 0; q < 4; ++q) {
                int c = tid + q * 256;
                int nI = c & 31, kI = c >> 5;
                const float* d0p = dbase + (size_t)(k0 + 2 * kI) * HDIM + 4 * nI;
                float4 d0 = *(const float4*)d0p;
                float4 d1 = *(const float4*)(d0p + HDIM);
                int n = 4 * nI;
                *(unsigned int*)&Bd[n + 0][2 * kI] = (unsigned)f2bf(d0.x) | ((unsigned)f2bf(d1.x) << 16);
                *(unsigned int*)&Bd[n + 1][2 * kI] = (unsigned)f2bf(d0.y) | ((unsigned)f2bf(d1.y) << 16);
                *(unsigned int*)&Bd[n + 2][2 * kI] = (unsigned)f2bf(d0.z) | ((unsigned)f2bf(d1.z) << 16);
                *(unsigned int*)&Bd[n + 3][2 * kI] = (unsigned)f2bf(d0.w) | ((unsigned)f2bf(d1.w) << 16);
            }
            __syncthreads();

            #pragma unroll
            for (int kk = 0; kk < 2; ++kk) {
                int krow = kk * 32 + lk;
                s16x8 a[4], b[4];
                #pragma unroll
                for (int mr = 0; mr < 4; ++mr)
                    a[mr] = *(const s16x8*)&As[wr * 64 + mr * 16 + l15][krow];
                #pragma unroll
                for (int nr = 0; nr < 4; ++nr)
                    b[nr] = *(const s16x8*)&Bd[wc * 64 + nr * 16 + l15][krow];
                #pragma unroll
                for (int mr = 0; mr < 4; ++mr)
                    #pragma unroll
                    for (int nr = 0; nr < 4; ++nr)
                        acc[mr][nr] = __builtin_amdgcn_mfma_f32_16x16x32_bf16(
                            a[mr], b[nr], acc[mr][nr], 0, 0, 0);
            }
            __syncthreads();
        }

        #pragma unroll
        for (int mr = 0; mr < 4; ++mr)
            #pragma unroll
            for (int nr = 0; nr < 4; ++nr) {
                int col = ntile * 128 + wc * 64 + nr * 16 + l15;
                #pragma unroll
                for (int reg = 0; reg < 4; ++reg) {
                    int r = m0 + wr * 64 + mr * 16 + (lane >> 4) * 4 + reg;
                    if (r < cnt)
                        partial[(size_t)(off + r) * HDIM + col] = f2bf(acc[mr][nr][reg]);
                }
            }
        // no LDS carried state besides tiles; sync before next mt staging
        __syncthreads();
    }
}

// ---------------- kernel 7: weighted 8-way reduce -> out ----------------
__global__ __launch_bounds__(256) void reduce_kernel(
    const unsigned short* __restrict__ partial, const int* __restrict__ slot_of,
    const float* __restrict__ topk_w, float* __restrict__ out) {
    int t = blockIdx.x;
    int j = blockIdx.y * 256 + threadIdx.x;
    __shared__ int ss[8];
    __shared__ float sw[8];
    if (threadIdx.x < 8) {
        ss[threadIdx.x] = slot_of[t * TOPK + threadIdx.x];
        sw[threadIdx.x] = topk_w[t * TOPK + threadIdx.x];
    }
    __syncthreads();
    float acc = 0.f;
    #pragma unroll
    for (int k = 0; k < TOPK; ++k) {
        unsigned short hb = partial[(size_t)ss[k] * HDIM + j];
        acc = fmaf(sw[k], bf_to_f(hb), acc);
    }
    out[(size_t)t * HDIM + j] = acc;
}

extern "C" void kernel_launch(void* const* d_in, const int* in_sizes, int n_in,
                              void* d_out, int out_size, void* d_ws, size_t ws_size,
                              hipStream_t stream) {
    const float* x  = (const float*)d_in[0];
    const float* rw = (const float*)d_in[1];
    const float* gw = (const float*)d_in[2];
    const float* uw = (const float*)d_in[3];
    const float* dw = (const float*)d_in[4];
    float* out = (float*)d_out;
    float* logits = out + OUT_OFF;

    char* ws = (char*)d_ws;
    int*   topk_idx   = (int*)(ws + WS_TOPK_IDX);
    float* topk_w     = (float*)(ws + WS_TOPK_W);
    int*   pair_token = (int*)(ws + WS_PAIR_TOK);
    int*   slot_of    = (int*)(ws + WS_SLOT_OF);
    int*   counts     = (int*)(ws + WS_COUNTS);
    int*   offsets    = (int*)(ws + WS_OFFSETS);
    int*   cursor     = (int*)(ws + WS_CURSOR);
    unsigned short* hbuf    = (unsigned short*)(ws + WS_H);
    unsigned short* partial = (unsigned short*)(ws + WS_PARTIAL);
    unsigned short* xb      = (unsigned short*)(ws + WS_XB);

    hipMemsetAsync(counts, 0, NEXP * sizeof(int), stream);
    xbf_kernel<<<T_TOK * HDIM / (256 * 8), 256, 0, stream>>>(x, xb);
    router_kernel<<<T_TOK / 4, 256, 0, stream>>>(x, rw, logits);
    topk_kernel<<<T_TOK, 64, 0, stream>>>(logits, topk_idx, topk_w, counts);
    scan_kernel<<<1, 64, 0, stream>>>(counts, offsets, cursor);
    scatter_kernel<<<NPAIR / 256, 256, 0, stream>>>(topk_idx, offsets, cursor, pair_token, slot_of);
    gateup_mfma<<<dim3(NEXP, 4, IDIM / 64), 256, 0, stream>>>(xb, gw, uw, offsets, pair_token, hbuf);
    down_mfma<<<dim3(NEXP, 4, HDIM / 128), 256, 0, stream>>>(hbuf, dw, offsets, partial);
    reduce_kernel<<<dim3(T_TOK, HDIM / 256), 256, 0, stream>>>(partial, slot_of, topk_w, out);
}

// Round 3
// 726.843 us; speedup vs baseline: 4.2621x; 1.2393x over previous
//
#include <hip/hip_runtime.h>
#include <hip/hip_bf16.h>

typedef __hip_bfloat16 bf16;
typedef short s16x8 __attribute__((ext_vector_type(8)));
typedef unsigned short u16x8 __attribute__((ext_vector_type(8)));
typedef float f32x4 __attribute__((ext_vector_type(4)));

#define T_TOK 2048
#define HDIM  2048
#define NEXP  64
#define IDIM  768
#define TOPK  8
#define OUT_OFF (T_TOK * HDIM)
#define NPAIR (T_TOK * TOPK)

#define WS_TOPK_IDX  0
#define WS_TOPK_W    (64 * 1024)
#define WS_PAIR_TOK  (128 * 1024)
#define WS_SLOT_OF   (192 * 1024)
#define WS_COUNTS    (256 * 1024)
#define WS_OFFSETS   (257 * 1024)
#define WS_CURSOR    (258 * 1024)
#define WS_H         (1024 * 1024)             // bf16 [NPAIR][IDIM]
#define WS_PARTIAL   (WS_H + (size_t)NPAIR * IDIM * 2)  // bf16 [NPAIR][HDIM]
#define WS_XB        WS_PARTIAL                // bf16 [T][H] (dead before partial written)

__device__ __forceinline__ float bf_to_f(unsigned short u) {
    return __uint_as_float(((unsigned int)u) << 16);
}
__device__ __forceinline__ unsigned short f2bf(float f) {
    unsigned int u = __float_as_uint(f);
    unsigned int r = (u + 0x7FFFu + ((u >> 16) & 1u)) >> 16;
    return (unsigned short)r;
}
__device__ __forceinline__ unsigned cvtpk(float lo, float hi) {
    unsigned r;
    asm("v_cvt_pk_bf16_f32 %0, %1, %2" : "=v"(r) : "v"(lo), "v"(hi));
    return r;
}

typedef const __attribute__((address_space(1))) unsigned int* gas_ptr;
typedef __attribute__((address_space(3))) unsigned int* las_ptr;
__device__ __forceinline__ void gload_lds16(const void* g, void* l) {
    __builtin_amdgcn_global_load_lds((gas_ptr)g, (las_ptr)l, 16, 0, 0);
}

// ---------------- kernel 0: x fp32 -> bf16 ----------------
__global__ __launch_bounds__(256) void xbf_kernel(const float* __restrict__ x,
                                                  unsigned short* __restrict__ xb) {
    int i = blockIdx.x * 256 + threadIdx.x;
    const float4* src = (const float4*)x + (size_t)i * 2;
    float4 a = src[0], b = src[1];
    u16x8 o;
    o[0] = f2bf(a.x); o[1] = f2bf(a.y); o[2] = f2bf(a.z); o[3] = f2bf(a.w);
    o[4] = f2bf(b.x); o[5] = f2bf(b.y); o[6] = f2bf(b.z); o[7] = f2bf(b.w);
    ((u16x8*)xb)[i] = o;
}

// ---------------- kernel 1: router logits ----------------
__global__ __launch_bounds__(256) void router_kernel(
    const float* __restrict__ x, const float* __restrict__ rw,
    float* __restrict__ logits) {
    int wave = threadIdx.x >> 6;
    int lane = threadIdx.x & 63;
    int t = blockIdx.x * 4 + wave;
    const float4* x4 = (const float4*)(x + (size_t)t * HDIM);
    float acc = 0.f;
    for (int h4 = 0; h4 < HDIM / 4; ++h4) {
        float4 xv = x4[h4];
        int h = h4 * 4;
        acc = fmaf(xv.x, rw[(h + 0) * NEXP + lane], acc);
        acc = fmaf(xv.y, rw[(h + 1) * NEXP + lane], acc);
        acc = fmaf(xv.z, rw[(h + 2) * NEXP + lane], acc);
        acc = fmaf(xv.w, rw[(h + 3) * NEXP + lane], acc);
    }
    logits[t * NEXP + lane] = acc;
}

// ---------------- kernel 2: softmax + top-8 ----------------
__global__ __launch_bounds__(64) void topk_kernel(
    const float* __restrict__ logits, int* __restrict__ topk_idx,
    float* __restrict__ topk_w, int* __restrict__ counts) {
    int t = blockIdx.x;
    int lane = threadIdx.x;
    float lg = logits[t * NEXP + lane];
    float mx = lg;
    for (int off = 32; off; off >>= 1) mx = fmaxf(mx, __shfl_xor(mx, off));
    float ex = expf(lg - mx);
    float sum = ex;
    for (int off = 32; off; off >>= 1) sum += __shfl_xor(sum, off);
    float prob = ex / sum;

    float pr = prob;
    float myv = 0.f;
    int myidx = 0;
    float ksum = 0.f;
    for (int k = 0; k < TOPK; ++k) {
        float v = pr;
        int idx = lane;
        for (int off = 32; off; off >>= 1) {
            float ov = __shfl_xor(v, off);
            int oi = __shfl_xor(idx, off);
            if (ov > v || (ov == v && oi < idx)) { v = ov; idx = oi; }
        }
        ksum += v;
        if (lane == k) { myidx = idx; myv = v; }
        if (lane == idx) pr = -1.f;
    }
    if (lane < TOPK) {
        topk_idx[t * TOPK + lane] = myidx;
        topk_w[t * TOPK + lane] = myv / ksum;
        atomicAdd(&counts[myidx], 1);
    }
}

// ---------------- kernel 3: scan ----------------
__global__ __launch_bounds__(64) void scan_kernel(
    const int* __restrict__ counts, int* __restrict__ offsets, int* __restrict__ cursor) {
    int lane = threadIdx.x;
    int c = counts[lane];
    int incl = c;
    for (int off = 1; off < 64; off <<= 1) {
        int tt = __shfl_up(incl, off);
        if (lane >= off) incl += tt;
    }
    offsets[lane] = incl - c;
    if (lane == 63) offsets[64] = incl;
    cursor[lane] = 0;
}

// ---------------- kernel 4: scatter ----------------
__global__ __launch_bounds__(256) void scatter_kernel(
    const int* __restrict__ topk_idx, const int* __restrict__ offsets,
    int* __restrict__ cursor, int* __restrict__ pair_token, int* __restrict__ slot_of) {
    int i = blockIdx.x * 256 + threadIdx.x;
    if (i >= NPAIR) return;
    int t = i >> 3;
    int e = topk_idx[i];
    int pos = atomicAdd(&cursor[e], 1);
    int slot = offsets[e] + pos;
    pair_token[slot] = t;
    slot_of[i] = slot;
}

// ================= MFMA grouped GEMMs =================
#define BM   128
#define BKS  64
#define LDP  72

// ---------------- kernel 5: gateup ----------------
// grid (e, mt4-stride, ntile 12); 256 thr = 4 waves (2x2); wave: 64m x 32n, g+u.
// A: global_load_lds (xor-swizzled src) dbuf. B: reg-stage fp32 -> cvt_pk -> LDS [n][k] dbuf.
// One barrier per K-step; next-step loads issued after barrier, in flight under MFMA.
__global__ __launch_bounds__(256) void gateup_mfma(
    const unsigned short* __restrict__ xb, const float* __restrict__ gate_w,
    const float* __restrict__ up_w, const int* __restrict__ offsets,
    const int* __restrict__ pair_token, unsigned short* __restrict__ hbuf) {
    int e = blockIdx.x;
    int ntile = blockIdx.z;
    int off = offsets[e];
    int cnt = offsets[e + 1] - off;
    if (cnt <= 0) return;

    __shared__ unsigned short As[2][BM * BKS];     // linear [m][64], src-swizzled
    __shared__ unsigned short Bg[2][64 * LDP];     // [n][k] padded
    __shared__ unsigned short Bu[2][64 * LDP];
    __shared__ int toks[BM];

    int tid = threadIdx.x;
    int lane = tid & 63;
    int wave = tid >> 6;
    int wr = wave >> 1, wc = wave & 1;
    int l15 = lane & 15, lg4 = lane >> 4;

    // B staging assignment: 256 cells = 16 nI x 16 kQ
    int nI = tid & 15, kQ = tid >> 4;
    int n4 = nI * 4, kB = kQ * 4;
    const float* gcol = gate_w + (size_t)e * HDIM * IDIM + ntile * 64 + (size_t)kB * IDIM + n4;
    const float* ucol = up_w   + (size_t)e * HDIM * IDIM + ntile * 64 + (size_t)kB * IDIM + n4;

    for (int mt = blockIdx.y; mt * BM < cnt; mt += gridDim.y) {
        int m0 = mt * BM;
        if (tid < BM) {
            int p = m0 + tid;
            toks[tid] = pair_token[off + (p < cnt ? p : 0)];
        }
        __syncthreads();
        // per-lane A source pointers (xor-swizzled chunk)
        const unsigned short* aq[4];
        #pragma unroll
        for (int q = 0; q < 4; ++q) {
            int mloc = q * 32 + wave * 8 + (lane >> 3);
            int j2 = (lane & 7) ^ (mloc & 7);
            aq[q] = xb + (size_t)toks[mloc] * HDIM + j2 * 8;
        }
        f32x4 accg[4][2] = {};
        f32x4 accu[4][2] = {};

        // prologue: issue A[0], load B[0] regs
        #pragma unroll
        for (int q = 0; q < 4; ++q)
            gload_lds16(aq[q], &As[0][(q * 256 + wave * 64) * 8]);
        float4 G[4], U[4];
        #pragma unroll
        for (int i = 0; i < 4; ++i) {
            G[i] = *(const float4*)(gcol + (size_t)i * IDIM);
            U[i] = *(const float4*)(ucol + (size_t)i * IDIM);
        }

        for (int ks = 0; ks < HDIM / BKS; ++ks) {
            int p = ks & 1;
            // 1. cvt+write B[ks] into buf p (uint2 = 2 k-pairs)
            #pragma unroll
            for (int j = 0; j < 4; ++j) {
                uint2 wg, wu;
                wg.x = cvtpk(((float*)&G[0])[j], ((float*)&G[1])[j]);
                wg.y = cvtpk(((float*)&G[2])[j], ((float*)&G[3])[j]);
                wu.x = cvtpk(((float*)&U[0])[j], ((float*)&U[1])[j]);
                wu.y = cvtpk(((float*)&U[2])[j], ((float*)&U[3])[j]);
                *(uint2*)&Bg[p][(n4 + j) * LDP + kB] = wg;
                *(uint2*)&Bu[p][(n4 + j) * LDP + kB] = wu;
            }
            // 2. barrier (implicit vmcnt(0) drains A[ks] lds-loads)
            __syncthreads();
            // 3. issue next-step loads (fly under MFMA)
            if (ks + 1 < HDIM / BKS) {
                int h1 = (ks + 1) * BKS;
                #pragma unroll
                for (int q = 0; q < 4; ++q)
                    gload_lds16(aq[q] + h1, &As[p ^ 1][(q * 256 + wave * 64) * 8]);
                #pragma unroll
                for (int i = 0; i < 4; ++i) {
                    G[i] = *(const float4*)(gcol + (size_t)(h1 + i) * IDIM);
                    U[i] = *(const float4*)(ucol + (size_t)(h1 + i) * IDIM);
                }
            }
            // 4. MFMA on buf p
            #pragma unroll
            for (int kk = 0; kk < 2; ++kk) {
                int krow = kk * 32 + lg4 * 8;
                int jk = kk * 4 + lg4;
                s16x8 a[4], bg2[2], bu2[2];
                #pragma unroll
                for (int mr = 0; mr < 4; ++mr) {
                    int r = wr * 64 + mr * 16 + l15;
                    a[mr] = *(const s16x8*)&As[p][r * 64 + ((jk ^ (r & 7)) * 8)];
                }
                #pragma unroll
                for (int nr = 0; nr < 2; ++nr) {
                    int row = wc * 32 + nr * 16 + l15;
                    bg2[nr] = *(const s16x8*)&Bg[p][row * LDP + krow];
                    bu2[nr] = *(const s16x8*)&Bu[p][row * LDP + krow];
                }
                #pragma unroll
                for (int mr = 0; mr < 4; ++mr)
                    #pragma unroll
                    for (int nr = 0; nr < 2; ++nr) {
                        accg[mr][nr] = __builtin_amdgcn_mfma_f32_16x16x32_bf16(
                            a[mr], bg2[nr], accg[mr][nr], 0, 0, 0);
                        accu[mr][nr] = __builtin_amdgcn_mfma_f32_16x16x32_bf16(
                            a[mr], bu2[nr], accu[mr][nr], 0, 0, 0);
                    }
            }
        }

        // epilogue: h = silu(g)*u
        #pragma unroll
        for (int mr = 0; mr < 4; ++mr)
            #pragma unroll
            for (int nr = 0; nr < 2; ++nr) {
                int col = ntile * 64 + wc * 32 + nr * 16 + l15;
                #pragma unroll
                for (int reg = 0; reg < 4; ++reg) {
                    int r = m0 + wr * 64 + mr * 16 + lg4 * 4 + reg;
                    if (r < cnt) {
                        float g = accg[mr][nr][reg];
                        float u = accu[mr][nr][reg];
                        float hv = (g / (1.f + __expf(-g))) * u;
                        hbuf[(size_t)(off + r) * IDIM + col] = f2bf(hv);
                    }
                }
            }
    }
}

// ---------------- kernel 6: down ----------------
// grid (e, mt4-stride, ntile 16); BN=128; waves 2x2, each 64x64.
__global__ __launch_bounds__(256) void down_mfma(
    const unsigned short* __restrict__ hbuf, const float* __restrict__ down_w,
    const int* __restrict__ offsets, unsigned short* __restrict__ partial) {
    int e = blockIdx.x;
    int ntile = blockIdx.z;
    int off = offsets[e];
    int cnt = offsets[e + 1] - off;
    if (cnt <= 0) return;

    __shared__ unsigned short As[2][BM * BKS];
    __shared__ unsigned short Bd[2][128 * LDP];

    int tid = threadIdx.x;
    int lane = tid & 63;
    int wave = tid >> 6;
    int wr = wave >> 1, wc = wave & 1;
    int l15 = lane & 15, lg4 = lane >> 4;

    // B staging: 512 cells = 32 nI x 16 kQ, 2 q-passes
    int nI = tid & 31, kQ0 = tid >> 5;       // kQ0 in 0..7; pass q adds 8
    int n4 = nI * 4;
    const float* dcol = down_w + (size_t)e * IDIM * HDIM + ntile * 128 + n4;

    for (int mt = blockIdx.y; mt * BM < cnt; mt += gridDim.y) {
        int m0 = mt * BM;
        const unsigned short* aq[4];
        #pragma unroll
        for (int q = 0; q < 4; ++q) {
            int mloc = q * 32 + wave * 8 + (lane >> 3);
            int row = m0 + mloc;
            if (row >= cnt) row = cnt - 1;
            int j2 = (lane & 7) ^ (mloc & 7);
            aq[q] = hbuf + (size_t)(off + row) * IDIM + j2 * 8;
        }
        f32x4 acc[4][4] = {};

        // prologue
        #pragma unroll
        for (int q = 0; q < 4; ++q)
            gload_lds16(aq[q], &As[0][(q * 256 + wave * 64) * 8]);
        float4 D0[4], D1[4];
        #pragma unroll
        for (int i = 0; i < 4; ++i) {
            D0[i] = *(const float4*)(dcol + (size_t)(kQ0 * 4 + i) * HDIM);
            D1[i] = *(const float4*)(dcol + (size_t)((kQ0 + 8) * 4 + i) * HDIM);
        }

        for (int ks = 0; ks < IDIM / BKS; ++ks) {
            int p = ks & 1;
            #pragma unroll
            for (int j = 0; j < 4; ++j) {
                uint2 w0, w1;
                w0.x = cvtpk(((float*)&D0[0])[j], ((float*)&D0[1])[j]);
                w0.y = cvtpk(((float*)&D0[2])[j], ((float*)&D0[3])[j]);
                w1.x = cvtpk(((float*)&D1[0])[j], ((float*)&D1[1])[j]);
                w1.y = cvtpk(((float*)&D1[2])[j], ((float*)&D1[3])[j]);
                *(uint2*)&Bd[p][(n4 + j) * LDP + kQ0 * 4] = w0;
                *(uint2*)&Bd[p][(n4 + j) * LDP + (kQ0 + 8) * 4] = w1;
            }
            __syncthreads();
            if (ks + 1 < IDIM / BKS) {
                int k1 = (ks + 1) * BKS;
                #pragma unroll
                for (int q = 0; q < 4; ++q)
                    gload_lds16(aq[q] + k1, &As[p ^ 1][(q * 256 + wave * 64) * 8]);
                #pragma unroll
                for (int i = 0; i < 4; ++i) {
                    D0[i] = *(const float4*)(dcol + (size_t)(k1 + kQ0 * 4 + i) * HDIM);
                    D1[i] = *(const float4*)(dcol + (size_t)(k1 + (kQ0 + 8) * 4 + i) * HDIM);
                }
            }
            #pragma unroll
            for (int kk = 0; kk < 2; ++kk) {
                int krow = kk * 32 + lg4 * 8;
                int jk = kk * 4 + lg4;
                s16x8 a[4], b[4];
                #pragma unroll
                for (int mr = 0; mr < 4; ++mr) {
                    int r = wr * 64 + mr * 16 + l15;
                    a[mr] = *(const s16x8*)&As[p][r * 64 + ((jk ^ (r & 7)) * 8)];
                }
                #pragma unroll
                for (int nr = 0; nr < 4; ++nr) {
                    int row = wc * 64 + nr * 16 + l15;
                    b[nr] = *(const s16x8*)&Bd[p][row * LDP + krow];
                }
                #pragma unroll
                for (int mr = 0; mr < 4; ++mr)
                    #pragma unroll
                    for (int nr = 0; nr < 4; ++nr)
                        acc[mr][nr] = __builtin_amdgcn_mfma_f32_16x16x32_bf16(
                            a[mr], b[nr], acc[mr][nr], 0, 0, 0);
            }
        }

        #pragma unroll
        for (int mr = 0; mr < 4; ++mr)
            #pragma unroll
            for (int nr = 0; nr < 4; ++nr) {
                int col = ntile * 128 + wc * 64 + nr * 16 + l15;
                #pragma unroll
                for (int reg = 0; reg < 4; ++reg) {
                    int r = m0 + wr * 64 + mr * 16 + lg4 * 4 + reg;
                    if (r < cnt)
                        partial[(size_t)(off + r) * HDIM + col] = f2bf(acc[mr][nr][reg]);
                }
            }
        __syncthreads();   // drain before next mt's A[0] issue into buf0
    }
}

// ---------------- kernel 7: weighted reduce ----------------
__global__ __launch_bounds__(256) void reduce_kernel(
    const unsigned short* __restrict__ partial, const int* __restrict__ slot_of,
    const float* __restrict__ topk_w, float* __restrict__ out) {
    int t = blockIdx.x;
    int j8 = threadIdx.x * 8;
    __shared__ int ss[8];
    __shared__ float sw[8];
    if (threadIdx.x < 8) {
        ss[threadIdx.x] = slot_of[t * TOPK + threadIdx.x];
        sw[threadIdx.x] = topk_w[t * TOPK + threadIdx.x];
    }
    __syncthreads();
    float acc[8] = {};
    #pragma unroll
    for (int k = 0; k < TOPK; ++k) {
        u16x8 v = *(const u16x8*)&partial[(size_t)ss[k] * HDIM + j8];
        float w = sw[k];
        #pragma unroll
        for (int i = 0; i < 8; ++i)
            acc[i] = fmaf(w, bf_to_f((unsigned short)v[i]), acc[i]);
    }
    float4 o0 = {acc[0], acc[1], acc[2], acc[3]};
    float4 o1 = {acc[4], acc[5], acc[6], acc[7]};
    *(float4*)&out[(size_t)t * HDIM + j8] = o0;
    *(float4*)&out[(size_t)t * HDIM + j8 + 4] = o1;
}

extern "C" void kernel_launch(void* const* d_in, const int* in_sizes, int n_in,
                              void* d_out, int out_size, void* d_ws, size_t ws_size,
                              hipStream_t stream) {
    const float* x  = (const float*)d_in[0];
    const float* rw = (const float*)d_in[1];
    const float* gw = (const float*)d_in[2];
    const float* uw = (const float*)d_in[3];
    const float* dw = (const float*)d_in[4];
    float* out = (float*)d_out;
    float* logits = out + OUT_OFF;

    char* ws = (char*)d_ws;
    int*   topk_idx   = (int*)(ws + WS_TOPK_IDX);
    float* topk_w     = (float*)(ws + WS_TOPK_W);
    int*   pair_token = (int*)(ws + WS_PAIR_TOK);
    int*   slot_of    = (int*)(ws + WS_SLOT_OF);
    int*   counts     = (int*)(ws + WS_COUNTS);
    int*   offsets    = (int*)(ws + WS_OFFSETS);
    int*   cursor     = (int*)(ws + WS_CURSOR);
    unsigned short* hbuf    = (unsigned short*)(ws + WS_H);
    unsigned short* partial = (unsigned short*)(ws + WS_PARTIAL);
    unsigned short* xb      = (unsigned short*)(ws + WS_XB);

    hipMemsetAsync(counts, 0, NEXP * sizeof(int), stream);
    xbf_kernel<<<T_TOK * HDIM / (256 * 8), 256, 0, stream>>>(x, xb);
    router_kernel<<<T_TOK / 4, 256, 0, stream>>>(x, rw, logits);
    topk_kernel<<<T_TOK, 64, 0, stream>>>(logits, topk_idx, topk_w, counts);
    scan_kernel<<<1, 64, 0, stream>>>(counts, offsets, cursor);
    scatter_kernel<<<NPAIR / 256, 256, 0, stream>>>(topk_idx, offsets, cursor, pair_token, slot_of);
    gateup_mfma<<<dim3(NEXP, 4, IDIM / 64), 256, 0, stream>>>(xb, gw, uw, offsets, pair_token, hbuf);
    down_mfma<<<dim3(NEXP, 4, HDIM / 128), 256, 0, stream>>>(hbuf, dw, offsets, partial);
    reduce_kernel<<<dim3(T_TOK, 1), 256, 0, stream>>>(partial, slot_of, topk_w, out);
}